// Round 7
// baseline (668.778 us; speedup 1.0000x reference)
//
#include <hip/hip_runtime.h>
#include <hip/hip_bf16.h>

// GCN 2-layer forward, two graphs, shared weights.
// R7: CSR build replaced by lean global-atomic grouping (SpMM only needs
//     edges grouped per row; within-row order was already nondeterministic):
//       prep_zero -> hist (global atomicAdd on counts[N]) -> scan over N
//       -> scatter (pos = atomicAdd(&cur[row],1); ecv[pos]={col,val}).
//     Removes coarse_scatter/fine_sort (52-73KB LDS, 2-3 blk/CU) and the
//     38MB ecvA round-trip. hist/scatter use ZERO LDS -> fat kernels pair
//     them with gemm tiles at uniform 36.9KB / 4 blk/CU.
//     role_gemm256 reverted to verified R5 W-in-LDS version (R6's W-from-
//     global regressed: no L1 shield under cache-hostile co-residency).
// GEMM: MFMA 16x16x32 bf16 split-bf16 3-term, 64x64 tile, LDS staging,
//     register A-prefetch. SpMM: R5-verified fused selu+W2 / norm kernels.

#define EPB 4096
#define GEMM_LDS 36864   // 4 * 64*72 shorts (Ah, Al, Wh, Wl)

typedef __attribute__((ext_vector_type(8))) short short8;
typedef __attribute__((ext_vector_type(4))) short short4v;
typedef __attribute__((ext_vector_type(4))) float f32x4;

__device__ __forceinline__ float selu_f(float x) {
    const float scale = 1.0507009873554805f;
    const float alpha = 1.6732632423543772f;
    return x > 0.0f ? scale * x : scale * alpha * (__expf(x) - 1.0f);
}

__device__ __forceinline__ short f2bf(float x) {   // RNE truncate fp32->bf16
    unsigned u = __float_as_uint(x);
    u += 0x7FFF + ((u >> 16) & 1);
    return (short)(u >> 16);
}
__device__ __forceinline__ float bf2f(short h) {
    return __uint_as_float(((unsigned)(unsigned short)h) << 16);
}

// ---------------- scan over counts[N] (batched over graphs, y) --------------
__global__ void scan_a(const int* __restrict__ countsB, int* __restrict__ offsB,
                       int* __restrict__ partialsB, int N) {
    const int* counts = countsB + (size_t)blockIdx.y * N;
    int* offs = offsB + (size_t)blockIdx.y * (N + 1);
    int* partials = partialsB + (size_t)blockIdx.y * 512;
    __shared__ int sh[256];
    int tid = threadIdx.x;
    int base = blockIdx.x * 1024 + tid * 4;
    int4 c = make_int4(0, 0, 0, 0);
    if (base + 3 < N) {
        c = *(const int4*)(counts + base);
    } else {
        if (base + 0 < N) c.x = counts[base + 0];
        if (base + 1 < N) c.y = counts[base + 1];
        if (base + 2 < N) c.z = counts[base + 2];
        if (base + 3 < N) c.w = counts[base + 3];
    }
    int tsum = c.x + c.y + c.z + c.w;
    sh[tid] = tsum;
    __syncthreads();
    int val = tsum;
    for (int d = 1; d < 256; d <<= 1) {
        int t = (tid >= d) ? sh[tid - d] : 0;
        __syncthreads();
        val += t;
        sh[tid] = val;
        __syncthreads();
    }
    int excl = val - tsum;
    int4 o;
    o.x = excl; o.y = o.x + c.x; o.z = o.y + c.y; o.w = o.z + c.z;
    if (base + 3 < N) {
        *(int4*)(offs + base) = o;
    } else {
        if (base + 0 < N) offs[base + 0] = o.x;
        if (base + 1 < N) offs[base + 1] = o.y;
        if (base + 2 < N) offs[base + 2] = o.z;
        if (base + 3 < N) offs[base + 3] = o.w;
    }
    if (tid == 255) partials[blockIdx.x] = val;
}

__global__ void scan_b(int* __restrict__ partialsB, int nb) {
    int* partials = partialsB + (size_t)blockIdx.y * 512;
    __shared__ int sh[128];
    int tid = threadIdx.x;
    int v = (tid < nb) ? partials[tid] : 0;
    sh[tid] = v;
    __syncthreads();
    int val = v;
    for (int d = 1; d < 128; d <<= 1) {
        int t = (tid >= d) ? sh[tid - d] : 0;
        __syncthreads();
        val += t;
        sh[tid] = val;
        __syncthreads();
    }
    if (tid < nb) partials[tid] = val - v;
}

// adds block offsets; also writes cur = offs (scatter cursors); offs[N]=E
__global__ void scan_c(int* __restrict__ offsB, int* __restrict__ curB,
                       const int* __restrict__ partialsB, int N, int E) {
    int* offs = offsB + (size_t)blockIdx.y * (N + 1);
    int* cur  = curB  + (size_t)blockIdx.y * N;
    const int* partials = partialsB + (size_t)blockIdx.y * 512;
    int tid = threadIdx.x;
    int base = blockIdx.x * 1024 + tid * 4;
    int add = partials[blockIdx.x];
    if (base + 3 < N) {
        int4 o = *(int4*)(offs + base);
        o.x += add; o.y += add; o.z += add; o.w += add;
        *(int4*)(offs + base) = o;
        *(int4*)(cur + base) = o;
    } else {
        for (int t = 0; t < 4; t++)
            if (base + t < N) {
                int v = offs[base + t] + add;
                offs[base + t] = v;
                cur[base + t] = v;
            }
    }
    if (blockIdx.x == 0 && tid == 0) offs[N] = E;
}

// ---------------- prep: weight split + zero counts (one dispatch) -----------
__global__ void prep_zero(const float* __restrict__ W1, short* __restrict__ th1,
                          short* __restrict__ tl1,
                          const float* __restrict__ W2, short* __restrict__ th2,
                          short* __restrict__ tl2,
                          int* __restrict__ counts2, int n2) {
    int idx = blockIdx.x * 256 + threadIdx.x;
    const int n1 = 256 * 64;
    if (idx < n1) {
        int k = idx >> 6, n = idx & 63;
        float x = W1[idx];
        short h = f2bf(x);
        short l = f2bf(x - bf2f(h));
        th1[n * 256 + k] = h;
        tl1[n * 256 + k] = l;
    } else if (idx - n1 < 64 * 64) {
        int i2 = idx - n1;
        int k = i2 >> 6, n = i2 & 63;
        float x = W2[i2];
        short h = f2bf(x);
        short l = f2bf(x - bf2f(h));
        th2[n * 64 + k] = h;
        tl2[n * 64 + k] = l;
    }
    for (int i = idx; i < n2; i += gridDim.x * 256) counts2[i] = 0;
}

// ================= device role bodies =============

// ---- role: histogram via global atomics (0 LDS) ----
__device__ __forceinline__ void role_hist(const int* __restrict__ rows,
                                          int* __restrict__ cnt,
                                          int E, int bx) {
    int tid = threadIdx.x;
    int e0 = bx * EPB;
#pragma unroll
    for (int k = 0; k < EPB / 1024; k++) {
        int e = e0 + (k * 256 + tid) * 4;
        if (e + 3 < E) {
            int4 r4 = *(const int4*)(rows + e);
            atomicAdd(&cnt[r4.x], 1);
            atomicAdd(&cnt[r4.y], 1);
            atomicAdd(&cnt[r4.z], 1);
            atomicAdd(&cnt[r4.w], 1);
        } else {
            for (int t = 0; t < 4; t++)
                if (e + t < E) atomicAdd(&cnt[rows[e + t]], 1);
        }
    }
}

// ---- role: grouping scatter via global cursors (0 LDS) ----
__device__ __forceinline__ void role_scatter(const int* __restrict__ rows,
                                             const int* __restrict__ cols,
                                             const float* __restrict__ vals,
                                             int* __restrict__ cur,
                                             int2* __restrict__ ecv,
                                             int E, int bx) {
    int tid = threadIdx.x;
    int e0 = bx * EPB;
#pragma unroll
    for (int k = 0; k < EPB / 1024; k++) {
        int e = e0 + (k * 256 + tid) * 4;
        if (e + 3 < E) {
            int4 r4 = *(const int4*)(rows + e);
            int4 c4 = *(const int4*)(cols + e);
            float4 v4 = *(const float4*)(vals + e);
            int p;
            p = atomicAdd(&cur[r4.x], 1); ecv[p] = make_int2(c4.x, __float_as_int(v4.x));
            p = atomicAdd(&cur[r4.y], 1); ecv[p] = make_int2(c4.y, __float_as_int(v4.y));
            p = atomicAdd(&cur[r4.z], 1); ecv[p] = make_int2(c4.z, __float_as_int(v4.z));
            p = atomicAdd(&cur[r4.w], 1); ecv[p] = make_int2(c4.w, __float_as_int(v4.w));
        } else {
            for (int t = 0; t < 4; t++)
                if (e + t < E) {
                    int p = atomicAdd(&cur[rows[e + t]], 1);
                    ecv[p] = make_int2(cols[e + t], __float_as_int(vals[e + t]));
                }
        }
    }
}

// ---- role: one 64x64 tile of C = A[M,256] @ W[256,64] (36.9KB LDS) ----
// R5-verified: A reg-prefetch across K-chunks, W staged in LDS (L1 shield).
__device__ __forceinline__ void role_gemm256(const float* __restrict__ A,
                                             const short* __restrict__ Wth,
                                             const short* __restrict__ Wtl,
                                             float* __restrict__ C, int M,
                                             int tile, char* smem) {
    constexpr int K = 256, NC = K / 64;
    short* Ah = (short*)smem;
    short* Al = Ah + 64 * 72;
    short* Wh = Al + 64 * 72;
    short* Wl = Wh + 64 * 72;
    int tid = threadIdx.x;
    int wave = tid >> 6, lane = tid & 63;
    int m = lane & 15, q = lane >> 4;
    int row0 = tile * 64;
    int ai = tid >> 4;
    int aj = (tid & 15) * 4;
    f32x4 acc[4] = {{0.f, 0.f, 0.f, 0.f}, {0.f, 0.f, 0.f, 0.f},
                    {0.f, 0.f, 0.f, 0.f}, {0.f, 0.f, 0.f, 0.f}};
    float4 ga[4];
#pragma unroll
    for (int v = 0; v < 4; v++) {
        int gr = row0 + v * 16 + ai;
        ga[v] = make_float4(0.f, 0.f, 0.f, 0.f);
        if (gr < M) ga[v] = *(const float4*)(A + (size_t)gr * K + aj);
    }
#pragma unroll
    for (int c = 0; c < NC; c++) {
        short4v whv[4], wlv[4];
#pragma unroll
        for (int v = 0; v < 4; v++) {
            size_t wo = (size_t)(v * 16 + ai) * K + c * 64 + aj;
            whv[v] = *(const short4v*)(Wth + wo);
            wlv[v] = *(const short4v*)(Wtl + wo);
        }
        float4 gan[4];
        if (c + 1 < NC) {
#pragma unroll
            for (int v = 0; v < 4; v++) {
                int gr = row0 + v * 16 + ai;
                gan[v] = make_float4(0.f, 0.f, 0.f, 0.f);
                if (gr < M)
                    gan[v] = *(const float4*)(A + (size_t)gr * K + (c + 1) * 64 + aj);
            }
        }
#pragma unroll
        for (int v = 0; v < 4; v++) {
            int r = v * 16 + ai;
            float f[4] = {ga[v].x, ga[v].y, ga[v].z, ga[v].w};
            short4v h, l;
#pragma unroll
            for (int j = 0; j < 4; j++) {
                short hh = f2bf(f[j]);
                h[j] = hh;
                l[j] = f2bf(f[j] - bf2f(hh));
            }
            *(short4v*)(&Ah[r * 72 + aj]) = h;
            *(short4v*)(&Al[r * 72 + aj]) = l;
        }
#pragma unroll
        for (int v = 0; v < 4; v++) {
            int n = v * 16 + ai;
            *(short4v*)(&Wh[n * 72 + aj]) = whv[v];
            *(short4v*)(&Wl[n * 72 + aj]) = wlv[v];
        }
        __syncthreads();
        int ar = (16 * wave + m) * 72;
        short8 ah0 = *(const short8*)(&Ah[ar + q * 8]);
        short8 ah1 = *(const short8*)(&Ah[ar + 32 + q * 8]);
        short8 al0 = *(const short8*)(&Al[ar + q * 8]);
        short8 al1 = *(const short8*)(&Al[ar + 32 + q * 8]);
#pragma unroll
        for (int nt = 0; nt < 4; nt++) {
            int nb = (nt * 16 + m) * 72;
            short8 bh0 = *(const short8*)(&Wh[nb + q * 8]);
            short8 bh1 = *(const short8*)(&Wh[nb + 32 + q * 8]);
            short8 bl0 = *(const short8*)(&Wl[nb + q * 8]);
            short8 bl1 = *(const short8*)(&Wl[nb + 32 + q * 8]);
            acc[nt] = __builtin_amdgcn_mfma_f32_16x16x32_bf16(ah0, bh0, acc[nt], 0, 0, 0);
            acc[nt] = __builtin_amdgcn_mfma_f32_16x16x32_bf16(al0, bh0, acc[nt], 0, 0, 0);
            acc[nt] = __builtin_amdgcn_mfma_f32_16x16x32_bf16(ah0, bl0, acc[nt], 0, 0, 0);
            acc[nt] = __builtin_amdgcn_mfma_f32_16x16x32_bf16(ah1, bh1, acc[nt], 0, 0, 0);
            acc[nt] = __builtin_amdgcn_mfma_f32_16x16x32_bf16(al1, bh1, acc[nt], 0, 0, 0);
            acc[nt] = __builtin_amdgcn_mfma_f32_16x16x32_bf16(ah1, bl1, acc[nt], 0, 0, 0);
        }
        if (c + 1 < NC) {
            __syncthreads();
#pragma unroll
            for (int v = 0; v < 4; v++) ga[v] = gan[v];
        }
    }
#pragma unroll
    for (int nt = 0; nt < 4; nt++) {
#pragma unroll
        for (int r = 0; r < 4; r++) {
            int grow = row0 + 16 * wave + q * 4 + r;
            if (grow < M) C[(size_t)grow * 64 + nt * 16 + m] = acc[nt][r];
        }
    }
}

// ================= fat kernels ==========

__global__ __launch_bounds__(256) void fat_hist_gemm(
        const int* __restrict__ r0, const int* __restrict__ r1,
        int* __restrict__ countsB, int E, int nbH,
        const float* __restrict__ X1, const float* __restrict__ X2,
        const short* __restrict__ w1th, const short* __restrict__ w1tl,
        float* __restrict__ C0, float* __restrict__ C1, int N,
        int t0, int tcnt) {
    __shared__ __align__(16) char smem[GEMM_LDS];
    int id = blockIdx.x;
    int nCsr = 2 * nbH;
    if (id < nCsr) {
        int g = id / nbH, bx = id % nbH;
        role_hist(g ? r1 : r0, countsB + (size_t)g * N, E, bx);
    } else {
        int gid = id - nCsr;
        int g = gid / tcnt;
        int tile = t0 + gid - g * tcnt;
        role_gemm256(g ? X2 : X1, w1th, w1tl, g ? C1 : C0, N, tile, smem);
    }
}

__global__ __launch_bounds__(256) void fat_scatter_gemm(
        const int* __restrict__ r0, const int* __restrict__ r1,
        const int* __restrict__ c0, const int* __restrict__ c1,
        const float* __restrict__ v0, const float* __restrict__ v1,
        int* __restrict__ curB, int2* __restrict__ ecvB, int E, int nbH,
        const float* __restrict__ X1, const float* __restrict__ X2,
        const short* __restrict__ w1th, const short* __restrict__ w1tl,
        float* __restrict__ C0, float* __restrict__ C1, int N,
        int t0, int tcnt) {
    __shared__ __align__(16) char smem[GEMM_LDS];
    int id = blockIdx.x;
    int nCsr = 2 * nbH;
    if (id < nCsr) {
        int g = id / nbH, bx = id % nbH;
        role_scatter(g ? r1 : r0, g ? c1 : c0, g ? v1 : v0,
                     curB + (size_t)g * N, ecvB + (size_t)g * E, E, bx);
    } else {
        int gid = id - nCsr;
        int g = gid / tcnt;
        int tile = t0 + gid - g * tcnt;
        role_gemm256(g ? X2 : X1, w1th, w1tl, g ? C1 : C0, N, tile, smem);
    }
}

// ---------------- SpMM core: one wave/row, 16 edges per iteration -----------
__device__ __forceinline__ void spmm_row4(const int* __restrict__ offs,
                                          const int2* __restrict__ ecv,
                                          const float* __restrict__ H,
                                          int row, int g, int f4,
                                          float& ax, float& ay, float& az, float& aw) {
    int s = offs[row], e = offs[row + 1];
    s = __builtin_amdgcn_readfirstlane(s);
    e = __builtin_amdgcn_readfirstlane(e);
    ax = ay = az = aw = 0.f;
    for (int i = s; i < e; i += 16) {
        int i0 = i + g, i1 = i + 4 + g, i2 = i + 8 + g, i3 = i + 12 + g;
        int2 p0 = ecv[i0 < e ? i0 : (e - 1)];
        int2 p1 = ecv[i1 < e ? i1 : (e - 1)];
        int2 p2 = ecv[i2 < e ? i2 : (e - 1)];
        int2 p3 = ecv[i3 < e ? i3 : (e - 1)];
        float v0 = (i0 < e) ? __int_as_float(p0.y) : 0.f;
        float v1 = (i1 < e) ? __int_as_float(p1.y) : 0.f;
        float v2 = (i2 < e) ? __int_as_float(p2.y) : 0.f;
        float v3 = (i3 < e) ? __int_as_float(p3.y) : 0.f;
        float4 h0 = *(const float4*)(H + (size_t)p0.x * 64 + f4);
        float4 h1 = *(const float4*)(H + (size_t)p1.x * 64 + f4);
        float4 h2 = *(const float4*)(H + (size_t)p2.x * 64 + f4);
        float4 h3 = *(const float4*)(H + (size_t)p3.x * 64 + f4);
        ax = fmaf(v0, h0.x, ax); ay = fmaf(v0, h0.y, ay);
        az = fmaf(v0, h0.z, az); aw = fmaf(v0, h0.w, aw);
        ax = fmaf(v1, h1.x, ax); ay = fmaf(v1, h1.y, ay);
        az = fmaf(v1, h1.z, az); aw = fmaf(v1, h1.w, aw);
        ax = fmaf(v2, h2.x, ax); ay = fmaf(v2, h2.y, ay);
        az = fmaf(v2, h2.z, az); aw = fmaf(v2, h2.w, aw);
        ax = fmaf(v3, h3.x, ax); ay = fmaf(v3, h3.y, ay);
        az = fmaf(v3, h3.z, az); aw = fmaf(v3, h3.w, aw);
    }
#pragma unroll
    for (int d = 16; d <= 32; d <<= 1) {
        ax += __shfl_xor(ax, d, 64);
        ay += __shfl_xor(ay, d, 64);
        az += __shfl_xor(az, d, 64);
        aw += __shfl_xor(aw, d, 64);
    }
}

// ---------------- fused: Z1 = selu(A@H + b1); Y = Z1 @ W2 -> out ------------
__global__ __launch_bounds__(256) void spmm_selu_w2(const int* __restrict__ offsB,
                                                    const int2* __restrict__ ecvB,
                                                    const float* __restrict__ HB,
                                                    const float* __restrict__ bias,
                                                    const short* __restrict__ w2th,
                                                    const short* __restrict__ w2tl,
                                                    float* __restrict__ outB,
                                                    int N, int E) {
    int gph = blockIdx.y;
    const int* offs = offsB + (size_t)gph * (N + 1);
    const int2* ecv = ecvB + (size_t)gph * E;
    const float* H = HB + (size_t)gph * N * 64;
    float* out = outB + (size_t)gph * N * 64;
    __shared__ short Zh[16 * 72], Zl[16 * 72];
    int tid = threadIdx.x, wave = tid >> 6, lane = tid & 63;
    int g = lane >> 4, f4 = (lane & 15) * 4;
    int rbase = blockIdx.x * 16;
    float4 b = *(const float4*)(bias + f4);
#pragma unroll
    for (int rr = 0; rr < 4; rr++) {
        int lr = wave * 4 + rr;
        int row = rbase + lr;
        if (row < N) {
            float ax, ay, az, aw;
            spmm_row4(offs, ecv, H, row, g, f4, ax, ay, az, aw);
            if (g == 0) {
                float zx = selu_f(ax + b.x);
                float zy = selu_f(ay + b.y);
                float zz = selu_f(az + b.z);
                float zw = selu_f(aw + b.w);
                short4v h, l;
                h.x = f2bf(zx); l.x = f2bf(zx - bf2f(h.x));
                h.y = f2bf(zy); l.y = f2bf(zy - bf2f(h.y));
                h.z = f2bf(zz); l.z = f2bf(zz - bf2f(h.z));
                h.w = f2bf(zw); l.w = f2bf(zw - bf2f(h.w));
                *(short4v*)(&Zh[lr * 72 + f4]) = h;
                *(short4v*)(&Zl[lr * 72 + f4]) = l;
            }
        } else if (g == 0) {
            short4v zv = {0, 0, 0, 0};
            *(short4v*)(&Zh[lr * 72 + f4]) = zv;
            *(short4v*)(&Zl[lr * 72 + f4]) = zv;
        }
    }
    __syncthreads();
    int m_ = lane & 15, q = lane >> 4;
    int ar = m_ * 72;
    short8 ah0 = *(const short8*)(&Zh[ar + q * 8]);
    short8 ah1 = *(const short8*)(&Zh[ar + 32 + q * 8]);
    short8 al0 = *(const short8*)(&Zl[ar + q * 8]);
    short8 al1 = *(const short8*)(&Zl[ar + 32 + q * 8]);
    const short* bhp = w2th + (size_t)(wave * 16 + m_) * 64;
    const short* blp = w2tl + (size_t)(wave * 16 + m_) * 64;
    short8 bh0 = *(const short8*)(bhp + q * 8);
    short8 bh1 = *(const short8*)(bhp + 32 + q * 8);
    short8 bl0 = *(const short8*)(blp + q * 8);
    short8 bl1 = *(const short8*)(blp + 32 + q * 8);
    f32x4 acc = {0.f, 0.f, 0.f, 0.f};
    acc = __builtin_amdgcn_mfma_f32_16x16x32_bf16(ah0, bh0, acc, 0, 0, 0);
    acc = __builtin_amdgcn_mfma_f32_16x16x32_bf16(al0, bh0, acc, 0, 0, 0);
    acc = __builtin_amdgcn_mfma_f32_16x16x32_bf16(ah0, bl0, acc, 0, 0, 0);
    acc = __builtin_amdgcn_mfma_f32_16x16x32_bf16(ah1, bh1, acc, 0, 0, 0);
    acc = __builtin_amdgcn_mfma_f32_16x16x32_bf16(al1, bh1, acc, 0, 0, 0);
    acc = __builtin_amdgcn_mfma_f32_16x16x32_bf16(ah1, bl1, acc, 0, 0, 0);
#pragma unroll
    for (int r = 0; r < 4; r++) {
        int grow = rbase + q * 4 + r;
        if (grow < N) out[(size_t)grow * 64 + wave * 16 + m_] = acc[r];
    }
}

// ---------------- spmm_norm: Z2 = A@Y + b2, row-L2-normalize ----------------
__global__ __launch_bounds__(256) void spmm_norm(const int* __restrict__ offsB,
                                                 const int2* __restrict__ ecvB,
                                                 const float* __restrict__ HB,
                                                 const float* __restrict__ bias,
                                                 float* __restrict__ outB,
                                                 int N, int E) {
    int gph = blockIdx.y;
    const int* offs = offsB + (size_t)gph * (N + 1);
    const int2* ecv = ecvB + (size_t)gph * E;
    const float* H = HB + (size_t)gph * N * 64;
    float* out = outB + (size_t)gph * N * 64;
    int row = blockIdx.x * 4 + (threadIdx.x >> 6);
    if (row >= N) return;
    int lane = threadIdx.x & 63;
    int g = lane >> 4, f4 = (lane & 15) * 4;
    float ax, ay, az, aw;
    spmm_row4(offs, ecv, H, row, g, f4, ax, ay, az, aw);
    float4 b = *(const float4*)(bias + f4);
    float zx = ax + b.x, zy = ay + b.y, zz = az + b.z, zw = aw + b.w;
    float s2 = zx * zx + zy * zy + zz * zz + zw * zw;
#pragma unroll
    for (int d = 1; d <= 8; d <<= 1) s2 += __shfl_xor(s2, d, 64);
    float inv = 1.0f / fmaxf(sqrtf(s2), 1e-12f);
    if (g == 0) {
        float4 o;
        o.x = zx * inv; o.y = zy * inv; o.z = zz * inv; o.w = zw * inv;
        *(float4*)(out + (size_t)row * 64 + f4) = o;
    }
}

extern "C" void kernel_launch(void* const* d_in, const int* in_sizes, int n_in,
                              void* d_out, int out_size, void* d_ws, size_t ws_size,
                              hipStream_t stream) {
    const int IN_DIM = 256, HID = 64;
    const int N = in_sizes[0] / IN_DIM;   // 100000
    const int E = in_sizes[2];            // 1200000

    const float* X1 = (const float*)d_in[0];
    const float* X2 = (const float*)d_in[1];
    const int*   r0 = (const int*)d_in[2];
    const int*   c0 = (const int*)d_in[3];
    const float* v0 = (const float*)d_in[4];
    const int*   r1 = (const int*)d_in[5];
    const int*   c1 = (const int*)d_in[6];
    const float* v1 = (const float*)d_in[7];
    const float* W1 = (const float*)d_in[8];
    const float* b1 = (const float*)d_in[9];
    const float* W2 = (const float*)d_in[10];
    const float* b2 = (const float*)d_in[11];
    float* out = (float*)d_out;

    const int nbH = (E + EPB - 1) / EPB;      // 293
    const int nbScanN = (N + 1023) / 1024;    // 98 (<=512 partials, <=128 scan_b)
    const int nbGemm = (N + 63) / 64;         // 1563
    const int nbRow  = (N + 3) / 4;           // 25000
    const int nbFuse = (N + 15) / 16;         // 6250

    // gemm tile split: fat1 (with short hist) gets ~60%, fat2 (scatter) ~40%
    const int Ta = (nbGemm * 3) / 5;          // 937
    const int Tb = nbGemm - Ta;               // 626

    auto align16 = [](char* p) { return (char*)(((uintptr_t)p + 15) & ~(uintptr_t)15); };
    char* w = (char*)d_ws;
    float* bufA   = (float*)w; w += (size_t)2 * N * HID * sizeof(float);
    float* bufB   = (float*)w; w += (size_t)2 * N * HID * sizeof(float);
    w = align16(w);
    int2*  ecv    = (int2*)w;  w += (size_t)2 * E * sizeof(int2);
    w = align16(w);
    int*   counts = (int*)w;   w += (size_t)2 * N * sizeof(int);
    w = align16(w);
    int*   offs   = (int*)w;   w += (size_t)2 * (N + 1) * sizeof(int);
    w = align16(w);
    int*   cur    = (int*)w;   w += (size_t)2 * N * sizeof(int);
    w = align16(w);
    int*   partials = (int*)w; w += 2 * 512 * sizeof(int);
    w = align16(w);
    short* w1th = (short*)w;   w += (size_t)64 * IN_DIM * sizeof(short);
    short* w1tl = (short*)w;   w += (size_t)64 * IN_DIM * sizeof(short);
    short* w2th = (short*)w;   w += (size_t)64 * HID * sizeof(short);
    short* w2tl = (short*)w;   w += (size_t)64 * HID * sizeof(short);
    float* bufA1 = bufA + (size_t)N * HID;

    // weight split + zero counts (one dispatch)
    prep_zero<<<400, 256, 0, stream>>>(W1, w1th, w1tl, W2, w2th, w2tl,
                                       counts, 2 * N);

    // fat1: global-atomic hist (both graphs) + gemm tiles [0, Ta)
    fat_hist_gemm<<<2 * nbH + 2 * Ta, 256, 0, stream>>>(
        r0, r1, counts, E, nbH,
        X1, X2, w1th, w1tl, bufA, bufA1, N, 0, Ta);

    // scan counts -> offs; scan_c also writes cursors
    scan_a<<<dim3(nbScanN, 2), 256, 0, stream>>>(counts, offs, partials, N);
    scan_b<<<dim3(1, 2), 128, 0, stream>>>(partials, nbScanN);
    scan_c<<<dim3(nbScanN, 2), 256, 0, stream>>>(offs, cur, partials, N, E);

    // fat2: cursor scatter (both graphs) + gemm tiles [Ta, nbGemm)
    fat_scatter_gemm<<<2 * nbH + 2 * Tb, 256, 0, stream>>>(
        r0, r1, c0, c1, v0, v1, cur, ecv, E, nbH,
        X1, X2, w1th, w1tl, bufA, bufA1, N, Ta, Tb);

    // fused: Z1 = selu(A@H + b1); Y = Z1@W2 -> bufB (both graphs)
    spmm_selu_w2<<<dim3(nbFuse, 2), 256, 0, stream>>>(offs, ecv, bufA, b1,
                                                      w2th, w2tl, bufB, N, E);
    // layer 2 aggregation + bias + L2 normalize -> out (both graphs)
    spmm_norm<<<dim3(nbRow, 2), 256, 0, stream>>>(offs, ecv, bufB, b2, out, N, E);
}

// Round 9
// 524.197 us; speedup vs baseline: 1.2758x; 1.2758x over previous
//
#include <hip/hip_runtime.h>
#include <hip/hip_bf16.h>

// GCN 2-layer forward, two graphs, shared weights.
// R9 = R8 with compile fix: __builtin_nontemporal_load cannot take int2*
//     (HIP vector type); load the 8-byte edge record as long long and unpack.
// R8 deltas vs verified R5 (504.5us):
//     (1) gemm tile split 156/703/704 -> 500/600/463: fat1 runs gemm at
//         4 blk/CU (36.9KB LDS) vs fat2's 3 (52KB) / fat3's 2 (72.7KB);
//     (2) non-temporal loads on the read-once ecv stream in SpMM -> keep
//         L2 for the randomly-gathered H rows.
//     LESSON (R1 + R7): random fine-grained global writes line-amplify ~8x;
//     the two-level LDS counting sort is mandatory, never raw global scatter.
// GEMM: MFMA 16x16x32 bf16 split-bf16 3-term, 64x64 tile, LDS staging for
//     A+W, register A-prefetch across K-chunks.
// spmm_selu_w2: fused Z1=selu(A@H+b1); Y=Z1@W2. spmm_norm: agg + L2-norm.

#define RPB 512
#define EPB 4096
#define MAXB 8192

typedef __attribute__((ext_vector_type(8))) short short8;
typedef __attribute__((ext_vector_type(4))) short short4v;
typedef __attribute__((ext_vector_type(4))) float f32x4;

#define GEMM_LDS 36864   // 4 * 64*72 shorts
#define SCAT_LDS 52224   // 3*1KB + 16KB + 32KB
#define SORT_LDS 72704   // 3*2KB + 1KB + 64KB

__device__ __forceinline__ float selu_f(float x) {
    const float scale = 1.0507009873554805f;
    const float alpha = 1.6732632423543772f;
    return x > 0.0f ? scale * x : scale * alpha * (__expf(x) - 1.0f);
}

__device__ __forceinline__ short f2bf(float x) {   // RNE truncate fp32->bf16
    unsigned u = __float_as_uint(x);
    u += 0x7FFF + ((u >> 16) & 1);
    return (short)(u >> 16);
}
__device__ __forceinline__ float bf2f(short h) {
    return __uint_as_float(((unsigned)(unsigned short)h) << 16);
}

// ---------------- scan (batched over graphs via blockIdx.y) ----------------
__global__ void scan_a(const int* __restrict__ countsB, int* __restrict__ offsB,
                       int* __restrict__ partialsB, int N) {
    const int* counts = countsB + (size_t)blockIdx.y * N;
    int* offs = offsB + (size_t)blockIdx.y * (N + 1);
    int* partials = partialsB + (size_t)blockIdx.y * 512;
    __shared__ int sh[256];
    int tid = threadIdx.x;
    int base = blockIdx.x * 1024 + tid * 4;
    int4 c = make_int4(0, 0, 0, 0);
    if (base + 3 < N) {
        c = *(const int4*)(counts + base);
    } else {
        if (base + 0 < N) c.x = counts[base + 0];
        if (base + 1 < N) c.y = counts[base + 1];
        if (base + 2 < N) c.z = counts[base + 2];
        if (base + 3 < N) c.w = counts[base + 3];
    }
    int tsum = c.x + c.y + c.z + c.w;
    sh[tid] = tsum;
    __syncthreads();
    int val = tsum;
    for (int d = 1; d < 256; d <<= 1) {
        int t = (tid >= d) ? sh[tid - d] : 0;
        __syncthreads();
        val += t;
        sh[tid] = val;
        __syncthreads();
    }
    int excl = val - tsum;
    int4 o;
    o.x = excl; o.y = o.x + c.x; o.z = o.y + c.y; o.w = o.z + c.z;
    if (base + 3 < N) {
        *(int4*)(offs + base) = o;
    } else {
        if (base + 0 < N) offs[base + 0] = o.x;
        if (base + 1 < N) offs[base + 1] = o.y;
        if (base + 2 < N) offs[base + 2] = o.z;
        if (base + 3 < N) offs[base + 3] = o.w;
    }
    if (tid == 255) partials[blockIdx.x] = val;
}

__global__ void scan_b(int* __restrict__ partialsB, int nb) {
    int* partials = partialsB + (size_t)blockIdx.y * 512;
    __shared__ int sh[128];
    int tid = threadIdx.x;
    int v = (tid < nb) ? partials[tid] : 0;
    sh[tid] = v;
    __syncthreads();
    int val = v;
    for (int d = 1; d < 128; d <<= 1) {
        int t = (tid >= d) ? sh[tid - d] : 0;
        __syncthreads();
        val += t;
        sh[tid] = val;
        __syncthreads();
    }
    if (tid < nb) partials[tid] = val - v;
}

__global__ void scan_c(int* __restrict__ offsB, const int* __restrict__ partialsB,
                       int N, int E) {
    int* offs = offsB + (size_t)blockIdx.y * (N + 1);
    const int* partials = partialsB + (size_t)blockIdx.y * 512;
    int tid = threadIdx.x;
    int base = blockIdx.x * 1024 + tid * 4;
    int add = partials[blockIdx.x];
    if (base + 3 < N) {
        int4 o = *(int4*)(offs + base);
        o.x += add; o.y += add; o.z += add; o.w += add;
        *(int4*)(offs + base) = o;
    } else {
        for (int t = 0; t < 4; t++)
            if (base + t < N) offs[base + t] += add;
    }
    if (blockIdx.x == 0 && tid == 0) offs[N] = E;
}

// ================= device role bodies =============

// ---- role: coarse histogram (1KB LDS) ----
__device__ __forceinline__ void role_hist(const int* __restrict__ rows,
                                          int* __restrict__ cntT,
                                          int E, int nbA, int NB, int bx,
                                          int* cnt) {
    int tid = threadIdx.x;
    cnt[tid] = 0;
    __syncthreads();
    int e0 = bx * EPB;
#pragma unroll
    for (int k = 0; k < EPB / 256; k++) {
        int e = e0 + k * 256 + tid;
        if (e < E) atomicAdd(&cnt[rows[e] >> 9], 1);
    }
    __syncthreads();
    if (tid < NB) cntT[tid * nbA + bx] = cnt[tid];
}

// ---- role: block-local counting sort (52KB LDS) ----
__device__ __forceinline__ void role_scatter(const int* __restrict__ rows,
                                             const int* __restrict__ cols,
                                             const float* __restrict__ vals,
                                             const int* __restrict__ csOffs,
                                             int2* __restrict__ ecvA,
                                             int E, int nbA, int NB, int bx,
                                             char* smem) {
    int* cnt = (int*)smem;
    int* loc = cnt + 256;
    int* gof = loc + 256;
    int* dstBase = gof + 256;
    int2* eLDS = (int2*)(dstBase + EPB);
    int tid = threadIdx.x;
    int e0 = bx * EPB;
    cnt[tid] = 0;
    __syncthreads();
#pragma unroll
    for (int k = 0; k < EPB / 256; k++) {
        int e = e0 + k * 256 + tid;
        if (e < E) atomicAdd(&cnt[rows[e] >> 9], 1);
    }
    __syncthreads();
    int my = cnt[tid];
    loc[tid] = my;
    __syncthreads();
    int val = my;
    for (int d = 1; d < 256; d <<= 1) {
        int t = (tid >= d) ? loc[tid - d] : 0;
        __syncthreads();
        val += t;
        loc[tid] = val;
        __syncthreads();
    }
    int excl = val - my;
    loc[tid] = excl;
    cnt[tid] = excl;
    gof[tid] = (tid < NB) ? csOffs[tid * nbA + bx] : 0;
    __syncthreads();
#pragma unroll
    for (int k = 0; k < EPB / 256; k++) {
        int e = e0 + k * 256 + tid;
        if (e < E) {
            int r = rows[e];
            int b = r >> 9;
            int p = atomicAdd(&cnt[b], 1);
            eLDS[p] = make_int2(((r & (RPB - 1)) << 17) | cols[e],
                                __float_as_int(vals[e]));
            dstBase[p] = gof[b] - loc[b];
        }
    }
    __syncthreads();
    int nE = min(EPB, E - e0);
    for (int j = tid; j < nE; j += 256)
        ecvA[dstBase[j] + j] = eLDS[j];
}

// ---- role: per-bucket fine sort (72.7KB LDS) ----
__device__ __forceinline__ void role_sort(const int* __restrict__ csOffs,
                                          const int2* __restrict__ ecvA,
                                          int2* __restrict__ ecv,
                                          int* __restrict__ offs,
                                          int nbA, int N, int E, int b,
                                          char* smem) {
    int* rcnt = (int*)smem;
    int* roff = rcnt + 512;
    int* rcur = roff + 512;
    int* sh   = rcur + 512;
    int2* eLDS = (int2*)(sh + 256);
    int tid = threadIdx.x;
    int bs = csOffs[b * nbA];
    int be = csOffs[(b + 1) * nbA];
    int cntE = be - bs;
    if (cntE > MAXB) cntE = MAXB;
    rcnt[tid] = 0;
    rcnt[tid + 256] = 0;
    __syncthreads();
    for (int j = tid; j < cntE; j += 256)
        atomicAdd(&rcnt[ecvA[bs + j].x >> 17], 1);
    __syncthreads();
    int a0 = rcnt[2 * tid], a1 = rcnt[2 * tid + 1];
    int ps = a0 + a1;
    sh[tid] = ps;
    __syncthreads();
    int val = ps;
    for (int d = 1; d < 256; d <<= 1) {
        int t = (tid >= d) ? sh[tid - d] : 0;
        __syncthreads();
        val += t;
        sh[tid] = val;
        __syncthreads();
    }
    int exclPair = val - ps;
    roff[2 * tid] = exclPair;
    roff[2 * tid + 1] = exclPair + a0;
    rcur[2 * tid] = exclPair;
    rcur[2 * tid + 1] = exclPair + a0;
    __syncthreads();
    int row0 = b * RPB;
    for (int t2 = tid; t2 < RPB; t2 += 256) {
        int row = row0 + t2;
        if (row <= N) offs[row] = bs + roff[t2];
    }
    if (b == 0 && tid == 0) offs[N] = E;
    for (int j = tid; j < cntE; j += 256) {
        int2 p = ecvA[bs + j];
        int pos = atomicAdd(&rcur[p.x >> 17], 1);
        if (pos < MAXB) eLDS[pos] = make_int2(p.x & 0x1FFFF, p.y);
    }
    __syncthreads();
    for (int j = tid; j < cntE; j += 256)
        ecv[bs + j] = eLDS[j];
}

// ---- role: one 64x64 tile of C = A[M,256] @ W[256,64] (36.9KB LDS) ----
__device__ __forceinline__ void role_gemm256(const float* __restrict__ A,
                                             const short* __restrict__ Wth,
                                             const short* __restrict__ Wtl,
                                             float* __restrict__ C, int M,
                                             int tile, char* smem) {
    constexpr int K = 256, NC = K / 64;
    short* Ah = (short*)smem;
    short* Al = Ah + 64 * 72;
    short* Wh = Al + 64 * 72;
    short* Wl = Wh + 64 * 72;
    int tid = threadIdx.x;
    int wave = tid >> 6, lane = tid & 63;
    int m = lane & 15, q = lane >> 4;
    int row0 = tile * 64;
    int ai = tid >> 4;
    int aj = (tid & 15) * 4;
    f32x4 acc[4] = {{0.f, 0.f, 0.f, 0.f}, {0.f, 0.f, 0.f, 0.f},
                    {0.f, 0.f, 0.f, 0.f}, {0.f, 0.f, 0.f, 0.f}};
    float4 ga[4];
#pragma unroll
    for (int v = 0; v < 4; v++) {
        int gr = row0 + v * 16 + ai;
        ga[v] = make_float4(0.f, 0.f, 0.f, 0.f);
        if (gr < M) ga[v] = *(const float4*)(A + (size_t)gr * K + aj);
    }
#pragma unroll
    for (int c = 0; c < NC; c++) {
        short4v whv[4], wlv[4];
#pragma unroll
        for (int v = 0; v < 4; v++) {
            size_t wo = (size_t)(v * 16 + ai) * K + c * 64 + aj;
            whv[v] = *(const short4v*)(Wth + wo);
            wlv[v] = *(const short4v*)(Wtl + wo);
        }
        float4 gan[4];
        if (c + 1 < NC) {
#pragma unroll
            for (int v = 0; v < 4; v++) {
                int gr = row0 + v * 16 + ai;
                gan[v] = make_float4(0.f, 0.f, 0.f, 0.f);
                if (gr < M)
                    gan[v] = *(const float4*)(A + (size_t)gr * K + (c + 1) * 64 + aj);
            }
        }
#pragma unroll
        for (int v = 0; v < 4; v++) {
            int r = v * 16 + ai;
            float f[4] = {ga[v].x, ga[v].y, ga[v].z, ga[v].w};
            short4v h, l;
#pragma unroll
            for (int j = 0; j < 4; j++) {
                short hh = f2bf(f[j]);
                h[j] = hh;
                l[j] = f2bf(f[j] - bf2f(hh));
            }
            *(short4v*)(&Ah[r * 72 + aj]) = h;
            *(short4v*)(&Al[r * 72 + aj]) = l;
        }
#pragma unroll
        for (int v = 0; v < 4; v++) {
            int n = v * 16 + ai;
            *(short4v*)(&Wh[n * 72 + aj]) = whv[v];
            *(short4v*)(&Wl[n * 72 + aj]) = wlv[v];
        }
        __syncthreads();
        int ar = (16 * wave + m) * 72;
        short8 ah0 = *(const short8*)(&Ah[ar + q * 8]);
        short8 ah1 = *(const short8*)(&Ah[ar + 32 + q * 8]);
        short8 al0 = *(const short8*)(&Al[ar + q * 8]);
        short8 al1 = *(const short8*)(&Al[ar + 32 + q * 8]);
#pragma unroll
        for (int nt = 0; nt < 4; nt++) {
            int nb = (nt * 16 + m) * 72;
            short8 bh0 = *(const short8*)(&Wh[nb + q * 8]);
            short8 bh1 = *(const short8*)(&Wh[nb + 32 + q * 8]);
            short8 bl0 = *(const short8*)(&Wl[nb + q * 8]);
            short8 bl1 = *(const short8*)(&Wl[nb + 32 + q * 8]);
            acc[nt] = __builtin_amdgcn_mfma_f32_16x16x32_bf16(ah0, bh0, acc[nt], 0, 0, 0);
            acc[nt] = __builtin_amdgcn_mfma_f32_16x16x32_bf16(al0, bh0, acc[nt], 0, 0, 0);
            acc[nt] = __builtin_amdgcn_mfma_f32_16x16x32_bf16(ah0, bl0, acc[nt], 0, 0, 0);
            acc[nt] = __builtin_amdgcn_mfma_f32_16x16x32_bf16(ah1, bh1, acc[nt], 0, 0, 0);
            acc[nt] = __builtin_amdgcn_mfma_f32_16x16x32_bf16(al1, bh1, acc[nt], 0, 0, 0);
            acc[nt] = __builtin_amdgcn_mfma_f32_16x16x32_bf16(ah1, bl1, acc[nt], 0, 0, 0);
        }
        if (c + 1 < NC) {
            __syncthreads();
#pragma unroll
            for (int v = 0; v < 4; v++) ga[v] = gan[v];
        }
    }
#pragma unroll
    for (int nt = 0; nt < 4; nt++) {
#pragma unroll
        for (int r = 0; r < 4; r++) {
            int grow = row0 + 16 * wave + q * 4 + r;
            if (grow < M) C[(size_t)grow * 64 + nt * 16 + m] = acc[nt][r];
        }
    }
}

// ================= fat kernels: CSR role (low blocks) + gemm slice ==========

__global__ __launch_bounds__(256) void fat_hist_gemm(
        const int* __restrict__ r0, const int* __restrict__ r1,
        int* __restrict__ cntTB, int E, int nbA, int NB, int Mcnt,
        const float* __restrict__ X1, const float* __restrict__ X2,
        const short* __restrict__ w1th, const short* __restrict__ w1tl,
        float* __restrict__ C0, float* __restrict__ C1, int Nn,
        int t0, int tcnt) {
    __shared__ __align__(16) char smem[GEMM_LDS];
    int id = blockIdx.x;
    int nCsr = 2 * nbA;
    if (id < nCsr) {
        int gph = id / nbA, bx = id % nbA;
        role_hist(gph ? r1 : r0, cntTB + (size_t)gph * Mcnt, E, nbA, NB, bx,
                  (int*)smem);
    } else {
        int gid = id - nCsr;
        int gph = gid / tcnt;
        int tile = t0 + gid - gph * tcnt;
        role_gemm256(gph ? X2 : X1, w1th, w1tl, gph ? C1 : C0, Nn, tile, smem);
    }
}

__global__ __launch_bounds__(256) void fat_scatter_gemm(
        const int* __restrict__ r0, const int* __restrict__ r1,
        const int* __restrict__ c0, const int* __restrict__ c1,
        const float* __restrict__ v0, const float* __restrict__ v1,
        const int* __restrict__ csOffsB, int2* __restrict__ ecvAB,
        int E, int nbA, int NB, int Mcnt,
        const float* __restrict__ X1, const float* __restrict__ X2,
        const short* __restrict__ w1th, const short* __restrict__ w1tl,
        float* __restrict__ C0, float* __restrict__ C1, int Nn,
        int t0, int tcnt) {
    __shared__ __align__(16) char smem[SCAT_LDS];
    int id = blockIdx.x;
    int nCsr = 2 * nbA;
    if (id < nCsr) {
        int gph = id / nbA, bx = id % nbA;
        role_scatter(gph ? r1 : r0, gph ? c1 : c0, gph ? v1 : v0,
                     csOffsB + (size_t)gph * (Mcnt + 1),
                     ecvAB + (size_t)gph * E, E, nbA, NB, bx, smem);
    } else {
        int gid = id - nCsr;
        int gph = gid / tcnt;
        int tile = t0 + gid - gph * tcnt;
        role_gemm256(gph ? X2 : X1, w1th, w1tl, gph ? C1 : C0, Nn, tile, smem);
    }
}

__global__ __launch_bounds__(256) void fat_sort_gemm(
        const int* __restrict__ csOffsB, const int2* __restrict__ ecvAB,
        int2* __restrict__ ecvB, int* __restrict__ offsB,
        int nbA, int N, int E, int Mcnt, int NB,
        const float* __restrict__ X1, const float* __restrict__ X2,
        const short* __restrict__ w1th, const short* __restrict__ w1tl,
        float* __restrict__ C0, float* __restrict__ C1, int Nn,
        int t0, int tcnt) {
    __shared__ __align__(16) char smem[SORT_LDS];
    int id = blockIdx.x;
    int nCsr = 2 * NB;
    if (id < nCsr) {
        int gph = id / NB, b = id % NB;
        role_sort(csOffsB + (size_t)gph * (Mcnt + 1),
                  ecvAB + (size_t)gph * E,
                  ecvB + (size_t)gph * E,
                  offsB + (size_t)gph * (N + 1),
                  nbA, N, E, b, smem);
    } else {
        int gid = id - nCsr;
        int gph = gid / tcnt;
        int tile = t0 + gid - gph * tcnt;
        role_gemm256(gph ? X2 : X1, w1th, w1tl, gph ? C1 : C0, Nn, tile, smem);
    }
}

// ---------------- weight prep: both weights in one dispatch ----------------
__global__ void prep_w2(const float* __restrict__ W1, short* __restrict__ th1,
                        short* __restrict__ tl1,
                        const float* __restrict__ W2, short* __restrict__ th2,
                        short* __restrict__ tl2) {
    int idx = blockIdx.x * 256 + threadIdx.x;
    const int n1 = 256 * 64;
    if (idx < n1) {
        int k = idx >> 6, n = idx & 63;
        float x = W1[idx];
        short h = f2bf(x);
        short l = f2bf(x - bf2f(h));
        th1[n * 256 + k] = h;
        tl1[n * 256 + k] = l;
    } else if (idx - n1 < 64 * 64) {
        int i2 = idx - n1;
        int k = i2 >> 6, n = i2 & 63;
        float x = W2[i2];
        short h = f2bf(x);
        short l = f2bf(x - bf2f(h));
        th2[n * 64 + k] = h;
        tl2[n * 64 + k] = l;
    }
}

// ---------------- SpMM core: one wave/row, 16 edges per iteration -----------
// ecv is a read-once stream: non-temporal loads (as long long; builtin rejects
// HIP vector types) keep L2 for the randomly-gathered H rows.
__device__ __forceinline__ void spmm_row4(const int* __restrict__ offs,
                                          const int2* __restrict__ ecv,
                                          const float* __restrict__ H,
                                          int row, int g, int f4,
                                          float& ax, float& ay, float& az, float& aw) {
    int s = offs[row], e = offs[row + 1];
    s = __builtin_amdgcn_readfirstlane(s);
    e = __builtin_amdgcn_readfirstlane(e);
    const long long* ecv8 = reinterpret_cast<const long long*>(ecv);
    ax = ay = az = aw = 0.f;
    for (int i = s; i < e; i += 16) {
        int i0 = i + g, i1 = i + 4 + g, i2 = i + 8 + g, i3 = i + 12 + g;
        long long q0 = __builtin_nontemporal_load(ecv8 + (i0 < e ? i0 : (e - 1)));
        long long q1 = __builtin_nontemporal_load(ecv8 + (i1 < e ? i1 : (e - 1)));
        long long q2 = __builtin_nontemporal_load(ecv8 + (i2 < e ? i2 : (e - 1)));
        long long q3 = __builtin_nontemporal_load(ecv8 + (i3 < e ? i3 : (e - 1)));
        int c0i = (int)(q0 & 0xFFFFFFFFll), c1i = (int)(q1 & 0xFFFFFFFFll);
        int c2i = (int)(q2 & 0xFFFFFFFFll), c3i = (int)(q3 & 0xFFFFFFFFll);
        float v0 = (i0 < e) ? __int_as_float((int)(q0 >> 32)) : 0.f;
        float v1 = (i1 < e) ? __int_as_float((int)(q1 >> 32)) : 0.f;
        float v2 = (i2 < e) ? __int_as_float((int)(q2 >> 32)) : 0.f;
        float v3 = (i3 < e) ? __int_as_float((int)(q3 >> 32)) : 0.f;
        float4 h0 = *(const float4*)(H + (size_t)c0i * 64 + f4);
        float4 h1 = *(const float4*)(H + (size_t)c1i * 64 + f4);
        float4 h2 = *(const float4*)(H + (size_t)c2i * 64 + f4);
        float4 h3 = *(const float4*)(H + (size_t)c3i * 64 + f4);
        ax = fmaf(v0, h0.x, ax); ay = fmaf(v0, h0.y, ay);
        az = fmaf(v0, h0.z, az); aw = fmaf(v0, h0.w, aw);
        ax = fmaf(v1, h1.x, ax); ay = fmaf(v1, h1.y, ay);
        az = fmaf(v1, h1.z, az); aw = fmaf(v1, h1.w, aw);
        ax = fmaf(v2, h2.x, ax); ay = fmaf(v2, h2.y, ay);
        az = fmaf(v2, h2.z, az); aw = fmaf(v2, h2.w, aw);
        ax = fmaf(v3, h3.x, ax); ay = fmaf(v3, h3.y, ay);
        az = fmaf(v3, h3.z, az); aw = fmaf(v3, h3.w, aw);
    }
#pragma unroll
    for (int d = 16; d <= 32; d <<= 1) {
        ax += __shfl_xor(ax, d, 64);
        ay += __shfl_xor(ay, d, 64);
        az += __shfl_xor(az, d, 64);
        aw += __shfl_xor(aw, d, 64);
    }
}

// ---------------- fused: Z1 = selu(A@H + b1); Y = Z1 @ W2 -> out ------------
__global__ __launch_bounds__(256) void spmm_selu_w2(const int* __restrict__ offsB,
                                                    const int2* __restrict__ ecvB,
                                                    const float* __restrict__ HB,
                                                    const float* __restrict__ bias,
                                                    const short* __restrict__ w2th,
                                                    const short* __restrict__ w2tl,
                                                    float* __restrict__ outB,
                                                    int N, int E) {
    int gph = blockIdx.y;
    const int* offs = offsB + (size_t)gph * (N + 1);
    const int2* ecv = ecvB + (size_t)gph * E;
    const float* H = HB + (size_t)gph * N * 64;
    float* out = outB + (size_t)gph * N * 64;
    __shared__ short Zh[16 * 72], Zl[16 * 72];
    int tid = threadIdx.x, wave = tid >> 6, lane = tid & 63;
    int g = lane >> 4, f4 = (lane & 15) * 4;
    int rbase = blockIdx.x * 16;
    float4 b = *(const float4*)(bias + f4);
#pragma unroll
    for (int rr = 0; rr < 4; rr++) {
        int lr = wave * 4 + rr;
        int row = rbase + lr;
        if (row < N) {
            float ax, ay, az, aw;
            spmm_row4(offs, ecv, H, row, g, f4, ax, ay, az, aw);
            if (g == 0) {
                float zx = selu_f(ax + b.x);
                float zy = selu_f(ay + b.y);
                float zz = selu_f(az + b.z);
                float zw = selu_f(aw + b.w);
                short4v h, l;
                h.x = f2bf(zx); l.x = f2bf(zx - bf2f(h.x));
                h.y = f2bf(zy); l.y = f2bf(zy - bf2f(h.y));
                h.z = f2bf(zz); l.z = f2bf(zz - bf2f(h.z));
                h.w = f2bf(zw); l.w = f2bf(zw - bf2f(h.w));
                *(short4v*)(&Zh[lr * 72 + f4]) = h;
                *(short4v*)(&Zl[lr * 72 + f4]) = l;
            }
        } else if (g == 0) {
            short4v zv = {0, 0, 0, 0};
            *(short4v*)(&Zh[lr * 72 + f4]) = zv;
            *(short4v*)(&Zl[lr * 72 + f4]) = zv;
        }
    }
    __syncthreads();
    int m_ = lane & 15, q = lane >> 4;
    int ar = m_ * 72;
    short8 ah0 = *(const short8*)(&Zh[ar + q * 8]);
    short8 ah1 = *(const short8*)(&Zh[ar + 32 + q * 8]);
    short8 al0 = *(const short8*)(&Zl[ar + q * 8]);
    short8 al1 = *(const short8*)(&Zl[ar + 32 + q * 8]);
    const short* bhp = w2th + (size_t)(wave * 16 + m_) * 64;
    const short* blp = w2tl + (size_t)(wave * 16 + m_) * 64;
    short8 bh0 = *(const short8*)(bhp + q * 8);
    short8 bh1 = *(const short8*)(bhp + 32 + q * 8);
    short8 bl0 = *(const short8*)(blp + q * 8);
    short8 bl1 = *(const short8*)(blp + 32 + q * 8);
    f32x4 acc = {0.f, 0.f, 0.f, 0.f};
    acc = __builtin_amdgcn_mfma_f32_16x16x32_bf16(ah0, bh0, acc, 0, 0, 0);
    acc = __builtin_amdgcn_mfma_f32_16x16x32_bf16(al0, bh0, acc, 0, 0, 0);
    acc = __builtin_amdgcn_mfma_f32_16x16x32_bf16(ah0, bl0, acc, 0, 0, 0);
    acc = __builtin_amdgcn_mfma_f32_16x16x32_bf16(ah1, bh1, acc, 0, 0, 0);
    acc = __builtin_amdgcn_mfma_f32_16x16x32_bf16(al1, bh1, acc, 0, 0, 0);
    acc = __builtin_amdgcn_mfma_f32_16x16x32_bf16(ah1, bl1, acc, 0, 0, 0);
#pragma unroll
    for (int r = 0; r < 4; r++) {
        int grow = rbase + q * 4 + r;
        if (grow < N) out[(size_t)grow * 64 + wave * 16 + m_] = acc[r];
    }
}

// ---------------- spmm_norm: Z2 = A@Y + b2, row-L2-normalize ----------------
__global__ __launch_bounds__(256) void spmm_norm(const int* __restrict__ offsB,
                                                 const int2* __restrict__ ecvB,
                                                 const float* __restrict__ HB,
                                                 const float* __restrict__ bias,
                                                 float* __restrict__ outB,
                                                 int N, int E) {
    int gph = blockIdx.y;
    const int* offs = offsB + (size_t)gph * (N + 1);
    const int2* ecv = ecvB + (size_t)gph * E;
    const float* H = HB + (size_t)gph * N * 64;
    float* out = outB + (size_t)gph * N * 64;
    int row = blockIdx.x * 4 + (threadIdx.x >> 6);
    if (row >= N) return;
    int lane = threadIdx.x & 63;
    int g = lane >> 4, f4 = (lane & 15) * 4;
    float ax, ay, az, aw;
    spmm_row4(offs, ecv, H, row, g, f4, ax, ay, az, aw);
    float4 b = *(const float4*)(bias + f4);
    float zx = ax + b.x, zy = ay + b.y, zz = az + b.z, zw = aw + b.w;
    float s2 = zx * zx + zy * zy + zz * zz + zw * zw;
#pragma unroll
    for (int d = 1; d <= 8; d <<= 1) s2 += __shfl_xor(s2, d, 64);
    float inv = 1.0f / fmaxf(sqrtf(s2), 1e-12f);
    if (g == 0) {
        float4 o;
        o.x = zx * inv; o.y = zy * inv; o.z = zz * inv; o.w = zw * inv;
        *(float4*)(out + (size_t)row * 64 + f4) = o;
    }
}

extern "C" void kernel_launch(void* const* d_in, const int* in_sizes, int n_in,
                              void* d_out, int out_size, void* d_ws, size_t ws_size,
                              hipStream_t stream) {
    const int IN_DIM = 256, HID = 64;
    const int N = in_sizes[0] / IN_DIM;   // 100000
    const int E = in_sizes[2];            // 1200000

    const float* X1 = (const float*)d_in[0];
    const float* X2 = (const float*)d_in[1];
    const int*   r0 = (const int*)d_in[2];
    const int*   c0 = (const int*)d_in[3];
    const float* v0 = (const float*)d_in[4];
    const int*   r1 = (const int*)d_in[5];
    const int*   c1 = (const int*)d_in[6];
    const float* v1 = (const float*)d_in[7];
    const float* W1 = (const float*)d_in[8];
    const float* b1 = (const float*)d_in[9];
    const float* W2 = (const float*)d_in[10];
    const float* b2 = (const float*)d_in[11];
    float* out = (float*)d_out;

    const int NB  = (N + RPB - 1) / RPB;      // 196
    const int nbA = (E + EPB - 1) / EPB;      // 293
    const int M   = NB * nbA;
    const int nbScanM = (M + 1023) / 1024;    // 57
    const int nbGemm = (N + 63) / 64;         // 1563
    const int nbRow  = (N + 3) / 4;           // 25000
    const int nbFuse = (N + 15) / 16;         // 6250

    // tile split: favor fat1 (gemm at 4 blk/CU there vs 3 / 2 in fat2/fat3)
    int Th  = nbGemm < 500 ? nbGemm : 500;
    int Tsc = (nbGemm - Th) < 600 ? (nbGemm - Th) : 600;
    int Tsr = nbGemm - Th - Tsc;              // 463

    auto align16 = [](char* p) { return (char*)(((uintptr_t)p + 15) & ~(uintptr_t)15); };
    char* w = (char*)d_ws;
    float* bufA   = (float*)w; w += (size_t)2 * N * HID * sizeof(float);
    float* bufB   = (float*)w; w += (size_t)2 * N * HID * sizeof(float);
    w = align16(w);
    int2*  ecv    = (int2*)w;  w += (size_t)2 * E * sizeof(int2);
    w = align16(w);
    int2*  ecvA   = (int2*)w;  w += (size_t)2 * E * sizeof(int2);
    w = align16(w);
    int*   cntT   = (int*)w;   w += (size_t)2 * M * sizeof(int);
    w = align16(w);
    int*   csOffs = (int*)w;   w += (size_t)2 * (M + 1) * sizeof(int);
    w = align16(w);
    int*   offs   = (int*)w;   w += (size_t)2 * (N + 1) * sizeof(int);
    w = align16(w);
    int*   partials = (int*)w; w += 2 * 512 * sizeof(int);
    w = align16(w);
    short* w1th = (short*)w;   w += (size_t)64 * IN_DIM * sizeof(short);
    short* w1tl = (short*)w;   w += (size_t)64 * IN_DIM * sizeof(short);
    short* w2th = (short*)w;   w += (size_t)64 * HID * sizeof(short);
    short* w2tl = (short*)w;   w += (size_t)64 * HID * sizeof(short);
    float* bufA1 = bufA + (size_t)N * HID;

    // weight prep (tiny; must precede fat1's gemm slice)
    prep_w2<<<(IN_DIM * 64 + HID * 64 + 255) / 256, 256, 0, stream>>>(
        W1, w1th, w1tl, W2, w2th, w2tl);

    // fat1: hist (both graphs) + gemm tiles [0, Th)
    fat_hist_gemm<<<2 * nbA + 2 * Th, 256, 0, stream>>>(
        r0, r1, cntT, E, nbA, NB, M,
        X1, X2, w1th, w1tl, bufA, bufA1, N, 0, Th);
    scan_a<<<dim3(nbScanM, 2), 256, 0, stream>>>(cntT, csOffs, partials, M);
    scan_b<<<dim3(1, 2), 128, 0, stream>>>(partials, nbScanM);
    scan_c<<<dim3(nbScanM, 2), 256, 0, stream>>>(csOffs, partials, M, E);
    // fat2: coarse scatter + gemm tiles [Th, Th+Tsc)
    fat_scatter_gemm<<<2 * nbA + 2 * Tsc, 256, 0, stream>>>(
        r0, r1, c0, c1, v0, v1, csOffs, ecvA, E, nbA, NB, M,
        X1, X2, w1th, w1tl, bufA, bufA1, N, Th, Tsc);
    // fat3: fine sort + gemm tiles [Th+Tsc, nbGemm)
    fat_sort_gemm<<<2 * NB + 2 * Tsr, 256, 0, stream>>>(
        csOffs, ecvA, ecv, offs, nbA, N, E, M, NB,
        X1, X2, w1th, w1tl, bufA, bufA1, N, Th + Tsc, Tsr);

    // fused: Z1 = selu(A@H + b1); Y = Z1@W2 -> bufB (both graphs)
    spmm_selu_w2<<<dim3(nbFuse, 2), 256, 0, stream>>>(offs, ecv, bufA, b1,
                                                      w2th, w2tl, bufB, N, E);
    // layer 2 aggregation + bias + L2 normalize -> out (both graphs)
    spmm_norm<<<dim3(nbRow, 2), 256, 0, stream>>>(offs, ecv, bufB, b2, out, N, E);
}

// Round 10
// 509.893 us; speedup vs baseline: 1.3116x; 1.0281x over previous
//
#include <hip/hip_runtime.h>
#include <hip/hip_bf16.h>

// GCN 2-layer forward, two graphs, shared weights.
// R10: revert R9's non-temporal ecv loads (regressed +16us on selu_w2:
//     ecv records are BROADCAST across 16-lane groups and line-shared across
//     rows -> NT bypass forces refetch; FETCH rose 275->283MB). Keep the
//     R8 tile rebalance (500/600/463) and de-aliased ecvA (both verified
//     neutral-to-positive in R9).
//     LESSONS: (R1,R7) random fine-grained global writes line-amplify ~8x ->
//     two-level LDS counting sort is mandatory. (R9) NT hints only for
//     truly private read-once streams, never broadcast/shared lines.
// GEMM: MFMA 16x16x32 bf16 split-bf16 3-term, 64x64 tile, LDS staging for
//     A+W, register A-prefetch across K-chunks.
// spmm_selu_w2: fused Z1=selu(A@H+b1); Y=Z1@W2. spmm_norm: agg + L2-norm.

#define RPB 512
#define EPB 4096
#define MAXB 8192

typedef __attribute__((ext_vector_type(8))) short short8;
typedef __attribute__((ext_vector_type(4))) short short4v;
typedef __attribute__((ext_vector_type(4))) float f32x4;

#define GEMM_LDS 36864   // 4 * 64*72 shorts
#define SCAT_LDS 52224   // 3*1KB + 16KB + 32KB
#define SORT_LDS 72704   // 3*2KB + 1KB + 64KB

__device__ __forceinline__ float selu_f(float x) {
    const float scale = 1.0507009873554805f;
    const float alpha = 1.6732632423543772f;
    return x > 0.0f ? scale * x : scale * alpha * (__expf(x) - 1.0f);
}

__device__ __forceinline__ short f2bf(float x) {   // RNE truncate fp32->bf16
    unsigned u = __float_as_uint(x);
    u += 0x7FFF + ((u >> 16) & 1);
    return (short)(u >> 16);
}
__device__ __forceinline__ float bf2f(short h) {
    return __uint_as_float(((unsigned)(unsigned short)h) << 16);
}

// ---------------- scan (batched over graphs via blockIdx.y) ----------------
__global__ void scan_a(const int* __restrict__ countsB, int* __restrict__ offsB,
                       int* __restrict__ partialsB, int N) {
    const int* counts = countsB + (size_t)blockIdx.y * N;
    int* offs = offsB + (size_t)blockIdx.y * (N + 1);
    int* partials = partialsB + (size_t)blockIdx.y * 512;
    __shared__ int sh[256];
    int tid = threadIdx.x;
    int base = blockIdx.x * 1024 + tid * 4;
    int4 c = make_int4(0, 0, 0, 0);
    if (base + 3 < N) {
        c = *(const int4*)(counts + base);
    } else {
        if (base + 0 < N) c.x = counts[base + 0];
        if (base + 1 < N) c.y = counts[base + 1];
        if (base + 2 < N) c.z = counts[base + 2];
        if (base + 3 < N) c.w = counts[base + 3];
    }
    int tsum = c.x + c.y + c.z + c.w;
    sh[tid] = tsum;
    __syncthreads();
    int val = tsum;
    for (int d = 1; d < 256; d <<= 1) {
        int t = (tid >= d) ? sh[tid - d] : 0;
        __syncthreads();
        val += t;
        sh[tid] = val;
        __syncthreads();
    }
    int excl = val - tsum;
    int4 o;
    o.x = excl; o.y = o.x + c.x; o.z = o.y + c.y; o.w = o.z + c.z;
    if (base + 3 < N) {
        *(int4*)(offs + base) = o;
    } else {
        if (base + 0 < N) offs[base + 0] = o.x;
        if (base + 1 < N) offs[base + 1] = o.y;
        if (base + 2 < N) offs[base + 2] = o.z;
        if (base + 3 < N) offs[base + 3] = o.w;
    }
    if (tid == 255) partials[blockIdx.x] = val;
}

__global__ void scan_b(int* __restrict__ partialsB, int nb) {
    int* partials = partialsB + (size_t)blockIdx.y * 512;
    __shared__ int sh[128];
    int tid = threadIdx.x;
    int v = (tid < nb) ? partials[tid] : 0;
    sh[tid] = v;
    __syncthreads();
    int val = v;
    for (int d = 1; d < 128; d <<= 1) {
        int t = (tid >= d) ? sh[tid - d] : 0;
        __syncthreads();
        val += t;
        sh[tid] = val;
        __syncthreads();
    }
    if (tid < nb) partials[tid] = val - v;
}

__global__ void scan_c(int* __restrict__ offsB, const int* __restrict__ partialsB,
                       int N, int E) {
    int* offs = offsB + (size_t)blockIdx.y * (N + 1);
    const int* partials = partialsB + (size_t)blockIdx.y * 512;
    int tid = threadIdx.x;
    int base = blockIdx.x * 1024 + tid * 4;
    int add = partials[blockIdx.x];
    if (base + 3 < N) {
        int4 o = *(int4*)(offs + base);
        o.x += add; o.y += add; o.z += add; o.w += add;
        *(int4*)(offs + base) = o;
    } else {
        for (int t = 0; t < 4; t++)
            if (base + t < N) offs[base + t] += add;
    }
    if (blockIdx.x == 0 && tid == 0) offs[N] = E;
}

// ================= device role bodies =============

// ---- role: coarse histogram (1KB LDS) ----
__device__ __forceinline__ void role_hist(const int* __restrict__ rows,
                                          int* __restrict__ cntT,
                                          int E, int nbA, int NB, int bx,
                                          int* cnt) {
    int tid = threadIdx.x;
    cnt[tid] = 0;
    __syncthreads();
    int e0 = bx * EPB;
#pragma unroll
    for (int k = 0; k < EPB / 256; k++) {
        int e = e0 + k * 256 + tid;
        if (e < E) atomicAdd(&cnt[rows[e] >> 9], 1);
    }
    __syncthreads();
    if (tid < NB) cntT[tid * nbA + bx] = cnt[tid];
}

// ---- role: block-local counting sort (52KB LDS) ----
__device__ __forceinline__ void role_scatter(const int* __restrict__ rows,
                                             const int* __restrict__ cols,
                                             const float* __restrict__ vals,
                                             const int* __restrict__ csOffs,
                                             int2* __restrict__ ecvA,
                                             int E, int nbA, int NB, int bx,
                                             char* smem) {
    int* cnt = (int*)smem;
    int* loc = cnt + 256;
    int* gof = loc + 256;
    int* dstBase = gof + 256;
    int2* eLDS = (int2*)(dstBase + EPB);
    int tid = threadIdx.x;
    int e0 = bx * EPB;
    cnt[tid] = 0;
    __syncthreads();
#pragma unroll
    for (int k = 0; k < EPB / 256; k++) {
        int e = e0 + k * 256 + tid;
        if (e < E) atomicAdd(&cnt[rows[e] >> 9], 1);
    }
    __syncthreads();
    int my = cnt[tid];
    loc[tid] = my;
    __syncthreads();
    int val = my;
    for (int d = 1; d < 256; d <<= 1) {
        int t = (tid >= d) ? loc[tid - d] : 0;
        __syncthreads();
        val += t;
        loc[tid] = val;
        __syncthreads();
    }
    int excl = val - my;
    loc[tid] = excl;
    cnt[tid] = excl;
    gof[tid] = (tid < NB) ? csOffs[tid * nbA + bx] : 0;
    __syncthreads();
#pragma unroll
    for (int k = 0; k < EPB / 256; k++) {
        int e = e0 + k * 256 + tid;
        if (e < E) {
            int r = rows[e];
            int b = r >> 9;
            int p = atomicAdd(&cnt[b], 1);
            eLDS[p] = make_int2(((r & (RPB - 1)) << 17) | cols[e],
                                __float_as_int(vals[e]));
            dstBase[p] = gof[b] - loc[b];
        }
    }
    __syncthreads();
    int nE = min(EPB, E - e0);
    for (int j = tid; j < nE; j += 256)
        ecvA[dstBase[j] + j] = eLDS[j];
}

// ---- role: per-bucket fine sort (72.7KB LDS) ----
__device__ __forceinline__ void role_sort(const int* __restrict__ csOffs,
                                          const int2* __restrict__ ecvA,
                                          int2* __restrict__ ecv,
                                          int* __restrict__ offs,
                                          int nbA, int N, int E, int b,
                                          char* smem) {
    int* rcnt = (int*)smem;
    int* roff = rcnt + 512;
    int* rcur = roff + 512;
    int* sh   = rcur + 512;
    int2* eLDS = (int2*)(sh + 256);
    int tid = threadIdx.x;
    int bs = csOffs[b * nbA];
    int be = csOffs[(b + 1) * nbA];
    int cntE = be - bs;
    if (cntE > MAXB) cntE = MAXB;
    rcnt[tid] = 0;
    rcnt[tid + 256] = 0;
    __syncthreads();
    for (int j = tid; j < cntE; j += 256)
        atomicAdd(&rcnt[ecvA[bs + j].x >> 17], 1);
    __syncthreads();
    int a0 = rcnt[2 * tid], a1 = rcnt[2 * tid + 1];
    int ps = a0 + a1;
    sh[tid] = ps;
    __syncthreads();
    int val = ps;
    for (int d = 1; d < 256; d <<= 1) {
        int t = (tid >= d) ? sh[tid - d] : 0;
        __syncthreads();
        val += t;
        sh[tid] = val;
        __syncthreads();
    }
    int exclPair = val - ps;
    roff[2 * tid] = exclPair;
    roff[2 * tid + 1] = exclPair + a0;
    rcur[2 * tid] = exclPair;
    rcur[2 * tid + 1] = exclPair + a0;
    __syncthreads();
    int row0 = b * RPB;
    for (int t2 = tid; t2 < RPB; t2 += 256) {
        int row = row0 + t2;
        if (row <= N) offs[row] = bs + roff[t2];
    }
    if (b == 0 && tid == 0) offs[N] = E;
    for (int j = tid; j < cntE; j += 256) {
        int2 p = ecvA[bs + j];
        int pos = atomicAdd(&rcur[p.x >> 17], 1);
        if (pos < MAXB) eLDS[pos] = make_int2(p.x & 0x1FFFF, p.y);
    }
    __syncthreads();
    for (int j = tid; j < cntE; j += 256)
        ecv[bs + j] = eLDS[j];
}

// ---- role: one 64x64 tile of C = A[M,256] @ W[256,64] (36.9KB LDS) ----
__device__ __forceinline__ void role_gemm256(const float* __restrict__ A,
                                             const short* __restrict__ Wth,
                                             const short* __restrict__ Wtl,
                                             float* __restrict__ C, int M,
                                             int tile, char* smem) {
    constexpr int K = 256, NC = K / 64;
    short* Ah = (short*)smem;
    short* Al = Ah + 64 * 72;
    short* Wh = Al + 64 * 72;
    short* Wl = Wh + 64 * 72;
    int tid = threadIdx.x;
    int wave = tid >> 6, lane = tid & 63;
    int m = lane & 15, q = lane >> 4;
    int row0 = tile * 64;
    int ai = tid >> 4;
    int aj = (tid & 15) * 4;
    f32x4 acc[4] = {{0.f, 0.f, 0.f, 0.f}, {0.f, 0.f, 0.f, 0.f},
                    {0.f, 0.f, 0.f, 0.f}, {0.f, 0.f, 0.f, 0.f}};
    float4 ga[4];
#pragma unroll
    for (int v = 0; v < 4; v++) {
        int gr = row0 + v * 16 + ai;
        ga[v] = make_float4(0.f, 0.f, 0.f, 0.f);
        if (gr < M) ga[v] = *(const float4*)(A + (size_t)gr * K + aj);
    }
#pragma unroll
    for (int c = 0; c < NC; c++) {
        short4v whv[4], wlv[4];
#pragma unroll
        for (int v = 0; v < 4; v++) {
            size_t wo = (size_t)(v * 16 + ai) * K + c * 64 + aj;
            whv[v] = *(const short4v*)(Wth + wo);
            wlv[v] = *(const short4v*)(Wtl + wo);
        }
        float4 gan[4];
        if (c + 1 < NC) {
#pragma unroll
            for (int v = 0; v < 4; v++) {
                int gr = row0 + v * 16 + ai;
                gan[v] = make_float4(0.f, 0.f, 0.f, 0.f);
                if (gr < M)
                    gan[v] = *(const float4*)(A + (size_t)gr * K + (c + 1) * 64 + aj);
            }
        }
#pragma unroll
        for (int v = 0; v < 4; v++) {
            int r = v * 16 + ai;
            float f[4] = {ga[v].x, ga[v].y, ga[v].z, ga[v].w};
            short4v h, l;
#pragma unroll
            for (int j = 0; j < 4; j++) {
                short hh = f2bf(f[j]);
                h[j] = hh;
                l[j] = f2bf(f[j] - bf2f(hh));
            }
            *(short4v*)(&Ah[r * 72 + aj]) = h;
            *(short4v*)(&Al[r * 72 + aj]) = l;
        }
#pragma unroll
        for (int v = 0; v < 4; v++) {
            int n = v * 16 + ai;
            *(short4v*)(&Wh[n * 72 + aj]) = whv[v];
            *(short4v*)(&Wl[n * 72 + aj]) = wlv[v];
        }
        __syncthreads();
        int ar = (16 * wave + m) * 72;
        short8 ah0 = *(const short8*)(&Ah[ar + q * 8]);
        short8 ah1 = *(const short8*)(&Ah[ar + 32 + q * 8]);
        short8 al0 = *(const short8*)(&Al[ar + q * 8]);
        short8 al1 = *(const short8*)(&Al[ar + 32 + q * 8]);
#pragma unroll
        for (int nt = 0; nt < 4; nt++) {
            int nb = (nt * 16 + m) * 72;
            short8 bh0 = *(const short8*)(&Wh[nb + q * 8]);
            short8 bh1 = *(const short8*)(&Wh[nb + 32 + q * 8]);
            short8 bl0 = *(const short8*)(&Wl[nb + q * 8]);
            short8 bl1 = *(const short8*)(&Wl[nb + 32 + q * 8]);
            acc[nt] = __builtin_amdgcn_mfma_f32_16x16x32_bf16(ah0, bh0, acc[nt], 0, 0, 0);
            acc[nt] = __builtin_amdgcn_mfma_f32_16x16x32_bf16(al0, bh0, acc[nt], 0, 0, 0);
            acc[nt] = __builtin_amdgcn_mfma_f32_16x16x32_bf16(ah0, bl0, acc[nt], 0, 0, 0);
            acc[nt] = __builtin_amdgcn_mfma_f32_16x16x32_bf16(ah1, bh1, acc[nt], 0, 0, 0);
            acc[nt] = __builtin_amdgcn_mfma_f32_16x16x32_bf16(al1, bh1, acc[nt], 0, 0, 0);
            acc[nt] = __builtin_amdgcn_mfma_f32_16x16x32_bf16(ah1, bl1, acc[nt], 0, 0, 0);
        }
        if (c + 1 < NC) {
            __syncthreads();
#pragma unroll
            for (int v = 0; v < 4; v++) ga[v] = gan[v];
        }
    }
#pragma unroll
    for (int nt = 0; nt < 4; nt++) {
#pragma unroll
        for (int r = 0; r < 4; r++) {
            int grow = row0 + 16 * wave + q * 4 + r;
            if (grow < M) C[(size_t)grow * 64 + nt * 16 + m] = acc[nt][r];
        }
    }
}

// ================= fat kernels: CSR role (low blocks) + gemm slice ==========

__global__ __launch_bounds__(256) void fat_hist_gemm(
        const int* __restrict__ r0, const int* __restrict__ r1,
        int* __restrict__ cntTB, int E, int nbA, int NB, int Mcnt,
        const float* __restrict__ X1, const float* __restrict__ X2,
        const short* __restrict__ w1th, const short* __restrict__ w1tl,
        float* __restrict__ C0, float* __restrict__ C1, int Nn,
        int t0, int tcnt) {
    __shared__ __align__(16) char smem[GEMM_LDS];
    int id = blockIdx.x;
    int nCsr = 2 * nbA;
    if (id < nCsr) {
        int gph = id / nbA, bx = id % nbA;
        role_hist(gph ? r1 : r0, cntTB + (size_t)gph * Mcnt, E, nbA, NB, bx,
                  (int*)smem);
    } else {
        int gid = id - nCsr;
        int gph = gid / tcnt;
        int tile = t0 + gid - gph * tcnt;
        role_gemm256(gph ? X2 : X1, w1th, w1tl, gph ? C1 : C0, Nn, tile, smem);
    }
}

__global__ __launch_bounds__(256) void fat_scatter_gemm(
        const int* __restrict__ r0, const int* __restrict__ r1,
        const int* __restrict__ c0, const int* __restrict__ c1,
        const float* __restrict__ v0, const float* __restrict__ v1,
        const int* __restrict__ csOffsB, int2* __restrict__ ecvAB,
        int E, int nbA, int NB, int Mcnt,
        const float* __restrict__ X1, const float* __restrict__ X2,
        const short* __restrict__ w1th, const short* __restrict__ w1tl,
        float* __restrict__ C0, float* __restrict__ C1, int Nn,
        int t0, int tcnt) {
    __shared__ __align__(16) char smem[SCAT_LDS];
    int id = blockIdx.x;
    int nCsr = 2 * nbA;
    if (id < nCsr) {
        int gph = id / nbA, bx = id % nbA;
        role_scatter(gph ? r1 : r0, gph ? c1 : c0, gph ? v1 : v0,
                     csOffsB + (size_t)gph * (Mcnt + 1),
                     ecvAB + (size_t)gph * E, E, nbA, NB, bx, smem);
    } else {
        int gid = id - nCsr;
        int gph = gid / tcnt;
        int tile = t0 + gid - gph * tcnt;
        role_gemm256(gph ? X2 : X1, w1th, w1tl, gph ? C1 : C0, Nn, tile, smem);
    }
}

__global__ __launch_bounds__(256) void fat_sort_gemm(
        const int* __restrict__ csOffsB, const int2* __restrict__ ecvAB,
        int2* __restrict__ ecvB, int* __restrict__ offsB,
        int nbA, int N, int E, int Mcnt, int NB,
        const float* __restrict__ X1, const float* __restrict__ X2,
        const short* __restrict__ w1th, const short* __restrict__ w1tl,
        float* __restrict__ C0, float* __restrict__ C1, int Nn,
        int t0, int tcnt) {
    __shared__ __align__(16) char smem[SORT_LDS];
    int id = blockIdx.x;
    int nCsr = 2 * NB;
    if (id < nCsr) {
        int gph = id / NB, b = id % NB;
        role_sort(csOffsB + (size_t)gph * (Mcnt + 1),
                  ecvAB + (size_t)gph * E,
                  ecvB + (size_t)gph * E,
                  offsB + (size_t)gph * (N + 1),
                  nbA, N, E, b, smem);
    } else {
        int gid = id - nCsr;
        int gph = gid / tcnt;
        int tile = t0 + gid - gph * tcnt;
        role_gemm256(gph ? X2 : X1, w1th, w1tl, gph ? C1 : C0, Nn, tile, smem);
    }
}

// ---------------- weight prep: both weights in one dispatch ----------------
__global__ void prep_w2(const float* __restrict__ W1, short* __restrict__ th1,
                        short* __restrict__ tl1,
                        const float* __restrict__ W2, short* __restrict__ th2,
                        short* __restrict__ tl2) {
    int idx = blockIdx.x * 256 + threadIdx.x;
    const int n1 = 256 * 64;
    if (idx < n1) {
        int k = idx >> 6, n = idx & 63;
        float x = W1[idx];
        short h = f2bf(x);
        short l = f2bf(x - bf2f(h));
        th1[n * 256 + k] = h;
        tl1[n * 256 + k] = l;
    } else if (idx - n1 < 64 * 64) {
        int i2 = idx - n1;
        int k = i2 >> 6, n = i2 & 63;
        float x = W2[i2];
        short h = f2bf(x);
        short l = f2bf(x - bf2f(h));
        th2[n * 64 + k] = h;
        tl2[n * 64 + k] = l;
    }
}

// ---------------- SpMM core: one wave/row, 16 edges per iteration -----------
__device__ __forceinline__ void spmm_row4(const int* __restrict__ offs,
                                          const int2* __restrict__ ecv,
                                          const float* __restrict__ H,
                                          int row, int g, int f4,
                                          float& ax, float& ay, float& az, float& aw) {
    int s = offs[row], e = offs[row + 1];
    s = __builtin_amdgcn_readfirstlane(s);
    e = __builtin_amdgcn_readfirstlane(e);
    ax = ay = az = aw = 0.f;
    for (int i = s; i < e; i += 16) {
        int i0 = i + g, i1 = i + 4 + g, i2 = i + 8 + g, i3 = i + 12 + g;
        int2 p0 = ecv[i0 < e ? i0 : (e - 1)];
        int2 p1 = ecv[i1 < e ? i1 : (e - 1)];
        int2 p2 = ecv[i2 < e ? i2 : (e - 1)];
        int2 p3 = ecv[i3 < e ? i3 : (e - 1)];
        float v0 = (i0 < e) ? __int_as_float(p0.y) : 0.f;
        float v1 = (i1 < e) ? __int_as_float(p1.y) : 0.f;
        float v2 = (i2 < e) ? __int_as_float(p2.y) : 0.f;
        float v3 = (i3 < e) ? __int_as_float(p3.y) : 0.f;
        float4 h0 = *(const float4*)(H + (size_t)p0.x * 64 + f4);
        float4 h1 = *(const float4*)(H + (size_t)p1.x * 64 + f4);
        float4 h2 = *(const float4*)(H + (size_t)p2.x * 64 + f4);
        float4 h3 = *(const float4*)(H + (size_t)p3.x * 64 + f4);
        ax = fmaf(v0, h0.x, ax); ay = fmaf(v0, h0.y, ay);
        az = fmaf(v0, h0.z, az); aw = fmaf(v0, h0.w, aw);
        ax = fmaf(v1, h1.x, ax); ay = fmaf(v1, h1.y, ay);
        az = fmaf(v1, h1.z, az); aw = fmaf(v1, h1.w, aw);
        ax = fmaf(v2, h2.x, ax); ay = fmaf(v2, h2.y, ay);
        az = fmaf(v2, h2.z, az); aw = fmaf(v2, h2.w, aw);
        ax = fmaf(v3, h3.x, ax); ay = fmaf(v3, h3.y, ay);
        az = fmaf(v3, h3.z, az); aw = fmaf(v3, h3.w, aw);
    }
#pragma unroll
    for (int d = 16; d <= 32; d <<= 1) {
        ax += __shfl_xor(ax, d, 64);
        ay += __shfl_xor(ay, d, 64);
        az += __shfl_xor(az, d, 64);
        aw += __shfl_xor(aw, d, 64);
    }
}

// ---------------- fused: Z1 = selu(A@H + b1); Y = Z1 @ W2 -> out ------------
__global__ __launch_bounds__(256) void spmm_selu_w2(const int* __restrict__ offsB,
                                                    const int2* __restrict__ ecvB,
                                                    const float* __restrict__ HB,
                                                    const float* __restrict__ bias,
                                                    const short* __restrict__ w2th,
                                                    const short* __restrict__ w2tl,
                                                    float* __restrict__ outB,
                                                    int N, int E) {
    int gph = blockIdx.y;
    const int* offs = offsB + (size_t)gph * (N + 1);
    const int2* ecv = ecvB + (size_t)gph * E;
    const float* H = HB + (size_t)gph * N * 64;
    float* out = outB + (size_t)gph * N * 64;
    __shared__ short Zh[16 * 72], Zl[16 * 72];
    int tid = threadIdx.x, wave = tid >> 6, lane = tid & 63;
    int g = lane >> 4, f4 = (lane & 15) * 4;
    int rbase = blockIdx.x * 16;
    float4 b = *(const float4*)(bias + f4);
#pragma unroll
    for (int rr = 0; rr < 4; rr++) {
        int lr = wave * 4 + rr;
        int row = rbase + lr;
        if (row < N) {
            float ax, ay, az, aw;
            spmm_row4(offs, ecv, H, row, g, f4, ax, ay, az, aw);
            if (g == 0) {
                float zx = selu_f(ax + b.x);
                float zy = selu_f(ay + b.y);
                float zz = selu_f(az + b.z);
                float zw = selu_f(aw + b.w);
                short4v h, l;
                h.x = f2bf(zx); l.x = f2bf(zx - bf2f(h.x));
                h.y = f2bf(zy); l.y = f2bf(zy - bf2f(h.y));
                h.z = f2bf(zz); l.z = f2bf(zz - bf2f(h.z));
                h.w = f2bf(zw); l.w = f2bf(zw - bf2f(h.w));
                *(short4v*)(&Zh[lr * 72 + f4]) = h;
                *(short4v*)(&Zl[lr * 72 + f4]) = l;
            }
        } else if (g == 0) {
            short4v zv = {0, 0, 0, 0};
            *(short4v*)(&Zh[lr * 72 + f4]) = zv;
            *(short4v*)(&Zl[lr * 72 + f4]) = zv;
        }
    }
    __syncthreads();
    int m_ = lane & 15, q = lane >> 4;
    int ar = m_ * 72;
    short8 ah0 = *(const short8*)(&Zh[ar + q * 8]);
    short8 ah1 = *(const short8*)(&Zh[ar + 32 + q * 8]);
    short8 al0 = *(const short8*)(&Zl[ar + q * 8]);
    short8 al1 = *(const short8*)(&Zl[ar + 32 + q * 8]);
    const short* bhp = w2th + (size_t)(wave * 16 + m_) * 64;
    const short* blp = w2tl + (size_t)(wave * 16 + m_) * 64;
    short8 bh0 = *(const short8*)(bhp + q * 8);
    short8 bh1 = *(const short8*)(bhp + 32 + q * 8);
    short8 bl0 = *(const short8*)(blp + q * 8);
    short8 bl1 = *(const short8*)(blp + 32 + q * 8);
    f32x4 acc = {0.f, 0.f, 0.f, 0.f};
    acc = __builtin_amdgcn_mfma_f32_16x16x32_bf16(ah0, bh0, acc, 0, 0, 0);
    acc = __builtin_amdgcn_mfma_f32_16x16x32_bf16(al0, bh0, acc, 0, 0, 0);
    acc = __builtin_amdgcn_mfma_f32_16x16x32_bf16(ah0, bl0, acc, 0, 0, 0);
    acc = __builtin_amdgcn_mfma_f32_16x16x32_bf16(ah1, bh1, acc, 0, 0, 0);
    acc = __builtin_amdgcn_mfma_f32_16x16x32_bf16(al1, bh1, acc, 0, 0, 0);
    acc = __builtin_amdgcn_mfma_f32_16x16x32_bf16(ah1, bl1, acc, 0, 0, 0);
#pragma unroll
    for (int r = 0; r < 4; r++) {
        int grow = rbase + q * 4 + r;
        if (grow < N) out[(size_t)grow * 64 + wave * 16 + m_] = acc[r];
    }
}

// ---------------- spmm_norm: Z2 = A@Y + b2, row-L2-normalize ----------------
__global__ __launch_bounds__(256) void spmm_norm(const int* __restrict__ offsB,
                                                 const int2* __restrict__ ecvB,
                                                 const float* __restrict__ HB,
                                                 const float* __restrict__ bias,
                                                 float* __restrict__ outB,
                                                 int N, int E) {
    int gph = blockIdx.y;
    const int* offs = offsB + (size_t)gph * (N + 1);
    const int2* ecv = ecvB + (size_t)gph * E;
    const float* H = HB + (size_t)gph * N * 64;
    float* out = outB + (size_t)gph * N * 64;
    int row = blockIdx.x * 4 + (threadIdx.x >> 6);
    if (row >= N) return;
    int lane = threadIdx.x & 63;
    int g = lane >> 4, f4 = (lane & 15) * 4;
    float ax, ay, az, aw;
    spmm_row4(offs, ecv, H, row, g, f4, ax, ay, az, aw);
    float4 b = *(const float4*)(bias + f4);
    float zx = ax + b.x, zy = ay + b.y, zz = az + b.z, zw = aw + b.w;
    float s2 = zx * zx + zy * zy + zz * zz + zw * zw;
#pragma unroll
    for (int d = 1; d <= 8; d <<= 1) s2 += __shfl_xor(s2, d, 64);
    float inv = 1.0f / fmaxf(sqrtf(s2), 1e-12f);
    if (g == 0) {
        float4 o;
        o.x = zx * inv; o.y = zy * inv; o.z = zz * inv; o.w = zw * inv;
        *(float4*)(out + (size_t)row * 64 + f4) = o;
    }
}

extern "C" void kernel_launch(void* const* d_in, const int* in_sizes, int n_in,
                              void* d_out, int out_size, void* d_ws, size_t ws_size,
                              hipStream_t stream) {
    const int IN_DIM = 256, HID = 64;
    const int N = in_sizes[0] / IN_DIM;   // 100000
    const int E = in_sizes[2];            // 1200000

    const float* X1 = (const float*)d_in[0];
    const float* X2 = (const float*)d_in[1];
    const int*   r0 = (const int*)d_in[2];
    const int*   c0 = (const int*)d_in[3];
    const float* v0 = (const float*)d_in[4];
    const int*   r1 = (const int*)d_in[5];
    const int*   c1 = (const int*)d_in[6];
    const float* v1 = (const float*)d_in[7];
    const float* W1 = (const float*)d_in[8];
    const float* b1 = (const float*)d_in[9];
    const float* W2 = (const float*)d_in[10];
    const float* b2 = (const float*)d_in[11];
    float* out = (float*)d_out;

    const int NB  = (N + RPB - 1) / RPB;      // 196
    const int nbA = (E + EPB - 1) / EPB;      // 293
    const int M   = NB * nbA;
    const int nbScanM = (M + 1023) / 1024;    // 57
    const int nbGemm = (N + 63) / 64;         // 1563
    const int nbRow  = (N + 3) / 4;           // 25000
    const int nbFuse = (N + 15) / 16;         // 6250

    // tile split: favor fat1 (gemm at 4 blk/CU there vs 3 / 2 in fat2/fat3)
    int Th  = nbGemm < 500 ? nbGemm : 500;
    int Tsc = (nbGemm - Th) < 600 ? (nbGemm - Th) : 600;
    int Tsr = nbGemm - Th - Tsc;              // 463

    auto align16 = [](char* p) { return (char*)(((uintptr_t)p + 15) & ~(uintptr_t)15); };
    char* w = (char*)d_ws;
    float* bufA   = (float*)w; w += (size_t)2 * N * HID * sizeof(float);
    float* bufB   = (float*)w; w += (size_t)2 * N * HID * sizeof(float);
    w = align16(w);
    int2*  ecv    = (int2*)w;  w += (size_t)2 * E * sizeof(int2);
    w = align16(w);
    int2*  ecvA   = (int2*)w;  w += (size_t)2 * E * sizeof(int2);
    w = align16(w);
    int*   cntT   = (int*)w;   w += (size_t)2 * M * sizeof(int);
    w = align16(w);
    int*   csOffs = (int*)w;   w += (size_t)2 * (M + 1) * sizeof(int);
    w = align16(w);
    int*   offs   = (int*)w;   w += (size_t)2 * (N + 1) * sizeof(int);
    w = align16(w);
    int*   partials = (int*)w; w += 2 * 512 * sizeof(int);
    w = align16(w);
    short* w1th = (short*)w;   w += (size_t)64 * IN_DIM * sizeof(short);
    short* w1tl = (short*)w;   w += (size_t)64 * IN_DIM * sizeof(short);
    short* w2th = (short*)w;   w += (size_t)64 * HID * sizeof(short);
    short* w2tl = (short*)w;   w += (size_t)64 * HID * sizeof(short);
    float* bufA1 = bufA + (size_t)N * HID;

    // weight prep (tiny; must precede fat1's gemm slice)
    prep_w2<<<(IN_DIM * 64 + HID * 64 + 255) / 256, 256, 0, stream>>>(
        W1, w1th, w1tl, W2, w2th, w2tl);

    // fat1: hist (both graphs) + gemm tiles [0, Th)
    fat_hist_gemm<<<2 * nbA + 2 * Th, 256, 0, stream>>>(
        r0, r1, cntT, E, nbA, NB, M,
        X1, X2, w1th, w1tl, bufA, bufA1, N, 0, Th);
    scan_a<<<dim3(nbScanM, 2), 256, 0, stream>>>(cntT, csOffs, partials, M);
    scan_b<<<dim3(1, 2), 128, 0, stream>>>(partials, nbScanM);
    scan_c<<<dim3(nbScanM, 2), 256, 0, stream>>>(csOffs, partials, M, E);
    // fat2: coarse scatter + gemm tiles [Th, Th+Tsc)
    fat_scatter_gemm<<<2 * nbA + 2 * Tsc, 256, 0, stream>>>(
        r0, r1, c0, c1, v0, v1, csOffs, ecvA, E, nbA, NB, M,
        X1, X2, w1th, w1tl, bufA, bufA1, N, Th, Tsc);
    // fat3: fine sort + gemm tiles [Th+Tsc, nbGemm)
    fat_sort_gemm<<<2 * NB + 2 * Tsr, 256, 0, stream>>>(
        csOffs, ecvA, ecv, offs, nbA, N, E, M, NB,
        X1, X2, w1th, w1tl, bufA, bufA1, N, Th + Tsc, Tsr);

    // fused: Z1 = selu(A@H + b1); Y = Z1@W2 -> bufB (both graphs)
    spmm_selu_w2<<<dim3(nbFuse, 2), 256, 0, stream>>>(offs, ecv, bufA, b1,
                                                      w2th, w2tl, bufB, N, E);
    // layer 2 aggregation + bias + L2 normalize -> out (both graphs)
    spmm_norm<<<dim3(nbRow, 2), 256, 0, stream>>>(offs, ecv, bufB, b2, out, N, E);
}